// Round 5
// baseline (6999.100 us; speedup 1.0000x reference)
//
#include <hip/hip_runtime.h>

#define B_ 64
#define T_ 383
#define S_ 384
#define ENC_ 768
#define TAGD_ 128
#define D_ 896
#define HG_ 400
#define HE_ 256
#define MSTEP_ 20
#define RTOT_ (B_*S_)                    // 24576
#define HEAD_SZ_ ((size_t)RTOT_*TAGD_)   // 3145728

typedef short short8 __attribute__((ext_vector_type(8)));
typedef float f32x4 __attribute__((ext_vector_type(4)));

__device__ __forceinline__ float bf2f(unsigned short u){
  union { unsigned int i; float f; } v; v.i = ((unsigned int)u) << 16; return v.f;
}
__device__ __forceinline__ float lo_f(unsigned int u){
  union { unsigned int i; float f; } v; v.i = u << 16; return v.f;
}
__device__ __forceinline__ float hi_f(unsigned int u){
  union { unsigned int i; float f; } v; v.i = u & 0xffff0000u; return v.f;
}
__device__ __forceinline__ unsigned short f2bf(float f){
  union { float f; unsigned int i; } v; v.f = f;
  unsigned int r = (v.i + 0x7fffu + ((v.i >> 16) & 1u)) >> 16;
  return (unsigned short)r;
}
__device__ __forceinline__ float tanh_fast(float x){
  float xc = fminf(fmaxf(x, -15.f), 15.f);
  float e = __expf(2.f*xc);
  return (e - 1.f) / (e + 1.f);
}

// ---------------------------------------------------------------------------
// Runtime MFMA C/D-layout discovery (probe MFMAs). Epilogues scatter via the
// discovered (row,col) maps, so no hard-coded fragment-layout assumption.
// ---------------------------------------------------------------------------
__device__ __forceinline__ void probe_maps(int lane, int* mlab, int* nlab){
  unsigned short lb = f2bf((float)(lane & 15));
  short8 av, bv;
  #pragma unroll
  for (int j = 0; j < 8; j++){ av[j] = (short)lb; bv[j] = (short)0x3F80; } // bf16(1.0)
  f32x4 z = {0.f,0.f,0.f,0.f};
  f32x4 d1 = __builtin_amdgcn_mfma_f32_16x16x32_bf16(av, bv, z, 0, 0, 0);
  f32x4 d2 = __builtin_amdgcn_mfma_f32_16x16x32_bf16(bv, av, z, 0, 0, 0);
  #pragma unroll
  for (int i = 0; i < 4; i++){
    mlab[i] = (int)(d1[i]*0.03125f + 0.5f);
    nlab[i] = (int)(d2[i]*0.03125f + 0.5f);
  }
}

// Generic float -> bf16 (n multiple of 4)
__global__ __launch_bounds__(256) void cvt4(const float* __restrict__ src,
                                            unsigned short* __restrict__ dst, int n4)
{
  int i = blockIdx.x*256 + threadIdx.x;
  if (i >= n4) return;
  float4 v = ((const float4*)src)[i];
  ((ushort4*)dst)[i] = make_ushort4(f2bf(v.x), f2bf(v.y), f2bf(v.z), f2bf(v.w));
}

// ---------------------------------------------------------------------------
// Pack Whh_f / Whh_b (float) into k-major bf16-pair layout for the RNN.
// ---------------------------------------------------------------------------
__global__ __launch_bounds__(256) void pack_whh(const float* __restrict__ Wf,
                                                const float* __restrict__ Wb,
                                                unsigned int* __restrict__ P)
{
  int idx = blockIdx.x*256 + threadIdx.x;
  if (idx >= 2*100*400) return;
  int dir = idx / 40000; int rem = idx % 40000;
  int kk = rem / 400;    int j   = rem % 400;
  const float* W = dir ? Wb : Wf;
  const float* src = W + (size_t)j*HG_ + kk*4;
  unsigned int p0 = (unsigned int)f2bf(src[0]) | ((unsigned int)f2bf(src[1]) << 16);
  unsigned int p1 = (unsigned int)f2bf(src[2]) | ((unsigned int)f2bf(src[3]) << 16);
  ((uint2*)P)[idx] = make_uint2(p0, p1);
}

// ---------------------------------------------------------------------------
// pre[r][n] (n<400: fwd, else bwd) = X[r].Wihcat[n] + bih[n] + bhh[n], bf16 out.
// X = concat(sentinel / input|tag) read from f32 inputs, cast inline.
// ---------------------------------------------------------------------------
__global__ __launch_bounds__(256) void gemm_pre(
    const float* __restrict__ inp, const float* __restrict__ tag,
    const float* __restrict__ sent, const unsigned short* __restrict__ W,
    const float* __restrict__ bihf, const float* __restrict__ bhhf,
    const float* __restrict__ bihb, const float* __restrict__ bhhb,
    unsigned short* __restrict__ preb)
{
  int wid = blockIdx.x*4 + (threadIdx.x >> 6);
  int lane = threadIdx.x & 63;
  int q = lane >> 4, l16 = lane & 15;
  int mt = wid / 25, ct = wid % 25;
  int r = mt*16 + l16;
  int s = r % S_, b = r / S_;
  int mlab[4], nlab[4];
  probe_maps(lane, mlab, nlab);
  int n0 = ct*32 + l16, n1 = n0 + 16;
  const unsigned short* w0 = W + (size_t)n0*D_;
  const unsigned short* w1 = W + (size_t)n1*D_;
  f32x4 acc0 = {0.f,0.f,0.f,0.f}, acc1 = {0.f,0.f,0.f,0.f};
  for (int k0 = 0; k0 < D_; k0 += 32){
    int k = k0 + q*8;   // 8-float group never straddles the 768 boundary
    const float* asrc = (s == 0) ? (sent + k)
        : ((k < ENC_) ? inp + (size_t)(b*T_ + (s-1))*ENC_ + k
                      : tag + (size_t)(b*T_ + (s-1))*TAGD_ + (k - ENC_));
    float4 v0 = *(const float4*)asrc;
    float4 v1 = *(const float4*)(asrc + 4);
    short8 a;
    a[0]=(short)f2bf(v0.x); a[1]=(short)f2bf(v0.y); a[2]=(short)f2bf(v0.z); a[3]=(short)f2bf(v0.w);
    a[4]=(short)f2bf(v1.x); a[5]=(short)f2bf(v1.y); a[6]=(short)f2bf(v1.z); a[7]=(short)f2bf(v1.w);
    acc0 = __builtin_amdgcn_mfma_f32_16x16x32_bf16(a, *(const short8*)(w0 + k), acc0, 0,0,0);
    acc1 = __builtin_amdgcn_mfma_f32_16x16x32_bf16(a, *(const short8*)(w1 + k), acc1, 0,0,0);
  }
  #pragma unroll
  for (int i = 0; i < 4; i++){
    int row = mt*16 + mlab[i];
    int c0 = ct*32 + nlab[i], c1 = c0 + 16;
    float bb0 = (c0 < HG_) ? (bihf[c0] + bhhf[c0]) : (bihb[c0-HG_] + bhhb[c0-HG_]);
    float bb1 = (c1 < HG_) ? (bihf[c1] + bhhf[c1]) : (bihb[c1-HG_] + bhhb[c1-HG_]);
    preb[(size_t)row*800 + c0] = f2bf(acc0[i] + bb0);
    preb[(size_t)row*800 + c1] = f2bf(acc1[i] + bb1);
  }
}

// ---------------------------------------------------------------------------
// Sequential masked RNN: one block per (direction, batch) chain.
// h fp32 in LDS; Whh bf16-packed streamed (coalesced); pre read as bf16.
// ---------------------------------------------------------------------------
__global__ __launch_bounds__(448) void rnn_kernel(
    const unsigned short* __restrict__ preb, const unsigned int* __restrict__ P,
    const int* __restrict__ mask, unsigned short* __restrict__ gs)
{
  __shared__ __align__(16) float hl[400];
  int j = threadIdx.x;
  int dir = blockIdx.x >> 6, b = blockIdx.x & 63;
  const uint2* P2 = (const uint2*)P + (size_t)dir*40000;
  float hold = 0.f;
  if (j < HG_) hl[j] = 0.f;
  __syncthreads();
  for (int stp = 0; stp < S_; stp++){
    int t = dir ? (S_-1-stp) : stp;
    float hn = 0.f;
    if (j < HG_){
      float acc = bf2f(preb[(size_t)(b*S_ + t)*800 + dir*HG_ + j]);
      #pragma unroll 4
      for (int kk = 0; kk < 100; kk++){
        float4 h4 = *(const float4*)&hl[kk*4];
        uint2 u = P2[kk*400 + j];
        acc += lo_f(u.x)*h4.x + hi_f(u.x)*h4.y + lo_f(u.y)*h4.z + hi_f(u.y)*h4.w;
      }
      hn = tanh_fast(acc);
    }
    float mval = (t > 0) ? (float)mask[b*T_ + (t-1)] : 1.f;
    float hnew = mval*hn + (1.f - mval)*hold;
    __syncthreads();            // all k-loop reads of hl done
    if (j < HG_){
      hl[j] = hnew; hold = hnew;
      gs[(size_t)(b*S_ + t)*800 + dir*HG_ + j] = f2bf(hnew*mval);
    }
    __syncthreads();
  }
}

// ---------------------------------------------------------------------------
// proj[r][n] = gs[r] . Wg2e[n] + bg2e[n]   (K=800, N=256), fp32 out
// ---------------------------------------------------------------------------
__global__ __launch_bounds__(256) void gemm_proj(
    const unsigned short* __restrict__ gs, const unsigned short* __restrict__ Wg2e,
    const float* __restrict__ bg2e, float* __restrict__ proj)
{
  int wid = blockIdx.x*4 + (threadIdx.x >> 6);
  int lane = threadIdx.x & 63;
  int q = lane >> 4, l16 = lane & 15;
  int mt = wid >> 3, ct = wid & 7;
  int mlab[4], nlab[4];
  probe_maps(lane, mlab, nlab);
  const unsigned short* arow = gs + (size_t)(mt*16 + l16)*800;
  int n0 = ct*32 + l16, n1 = n0 + 16;
  const unsigned short* w0 = Wg2e + (size_t)n0*800;
  const unsigned short* w1 = Wg2e + (size_t)n1*800;
  f32x4 acc0 = {0.f,0.f,0.f,0.f}, acc1 = {0.f,0.f,0.f,0.f};
  for (int k0 = 0; k0 < 800; k0 += 32){
    int k = k0 + q*8;
    short8 a = *(const short8*)(arow + k);
    acc0 = __builtin_amdgcn_mfma_f32_16x16x32_bf16(a, *(const short8*)(w0 + k), acc0, 0,0,0);
    acc1 = __builtin_amdgcn_mfma_f32_16x16x32_bf16(a, *(const short8*)(w1 + k), acc1, 0,0,0);
  }
  #pragma unroll
  for (int i = 0; i < 4; i++){
    int row = mt*16 + mlab[i];
    int c0 = ct*32 + nlab[i], c1 = c0 + 16;
    proj[(size_t)row*HE_ + c0] = acc0[i] + bg2e[c0];
    proj[(size_t)row*HE_ + c1] = acc1[i] + bg2e[c1];
  }
}

// ---------------------------------------------------------------------------
// head_tag / dep_tag = elu(gs @ Wtag^T + b), N=256 (c<128 head, else dep).
// *** float32 stores into d_out (the reference's output dtype). ***
// ---------------------------------------------------------------------------
__global__ __launch_bounds__(256) void gemm_tag(
    const unsigned short* __restrict__ gs, const unsigned short* __restrict__ Wtag,
    const float* __restrict__ bht, const float* __restrict__ bdt,
    float* __restrict__ outH)
{
  int wid = blockIdx.x*4 + (threadIdx.x >> 6);
  int lane = threadIdx.x & 63;
  int q = lane >> 4, l16 = lane & 15;
  int mt = wid >> 3, ct = wid & 7;
  int mlab[4], nlab[4];
  probe_maps(lane, mlab, nlab);
  const unsigned short* arow = gs + (size_t)(mt*16 + l16)*800;
  int n0 = ct*32 + l16, n1 = n0 + 16;
  const unsigned short* w0 = Wtag + (size_t)n0*800;
  const unsigned short* w1 = Wtag + (size_t)n1*800;
  f32x4 acc0 = {0.f,0.f,0.f,0.f}, acc1 = {0.f,0.f,0.f,0.f};
  for (int k0 = 0; k0 < 800; k0 += 32){
    int k = k0 + q*8;
    short8 a = *(const short8*)(arow + k);
    acc0 = __builtin_amdgcn_mfma_f32_16x16x32_bf16(a, *(const short8*)(w0 + k), acc0, 0,0,0);
    acc1 = __builtin_amdgcn_mfma_f32_16x16x32_bf16(a, *(const short8*)(w1 + k), acc1, 0,0,0);
  }
  #pragma unroll
  for (int i = 0; i < 4; i++){
    int row = mt*16 + mlab[i];
    int c0 = ct*32 + nlab[i], c1 = c0 + 16;
    float v0 = acc0[i] + ((c0 < TAGD_) ? bht[c0] : bdt[c0-TAGD_]);
    float v1 = acc1[i] + ((c1 < TAGD_) ? bht[c1] : bdt[c1-TAGD_]);
    v0 = (v0 > 0.f) ? v0 : expm1f(v0);
    v1 = (v1 > 0.f) ? v1 : expm1f(v1);
    if (c0 < TAGD_) outH[(size_t)row*TAGD_ + c0] = v0;
    else            outH[HEAD_SZ_ + (size_t)row*TAGD_ + (c0-TAGD_)] = v0;
    if (c1 < TAGD_) outH[(size_t)row*TAGD_ + c1] = v1;
    else            outH[HEAD_SZ_ + (size_t)row*TAGD_ + (c1-TAGD_)] = v1;
  }
}

// ---------------------------------------------------------------------------
// estep scan: each wave owns 16 rows, fully wave-private (no __syncthreads).
// H tile (16x256 bf16) in padded LDS; logit reduce via LDS atomicAdd.
// ---------------------------------------------------------------------------
#define HSTR 264  // shorts per LDS row (256 + 8 pad)
__global__ __launch_bounds__(256) void estep_kernel(
    const float* __restrict__ proj, const unsigned short* __restrict__ WhhE,
    const float* __restrict__ bihE, const float* __restrict__ bhhE,
    const float* __restrict__ WihE, const float* __restrict__ Wcls,
    const float* __restrict__ bclsp, const float* __restrict__ bosp,
    float* __restrict__ Ap)
{
  __shared__ __align__(16) unsigned short H[4][16][HSTR];
  __shared__ float xls[4][16];
  __shared__ float lacc[4][16];
  int wave = threadIdx.x >> 6, lane = threadIdx.x & 63;
  int q = lane >> 4, l16 = lane & 15;
  int rowbase = (blockIdx.x*4 + wave)*16;
  int mlab[4], nlab[4];
  probe_maps(lane, mlab, nlab);
  for (int i = lane; i < 16*HE_; i += 64){
    int m = i >> 8, n = i & 255;
    H[wave][m][n] = f2bf(proj[(size_t)(rowbase+m)*HE_ + n]);
  }
  if (lane < 16){ xls[wave][lane] = bosp[0]; lacc[wave][lane] = 0.f; }
  float bc = bclsp[0];
  for (int stp = 0; stp < MSTEP_; stp++){
    short8 af[8];
    #pragma unroll
    for (int kt = 0; kt < 8; kt++)
      af[kt] = *(const short8*)&H[wave][l16][kt*32 + q*8];
    float xr[4];
    #pragma unroll
    for (int ri = 0; ri < 4; ri++) xr[ri] = xls[wave][mlab[ri]];
    float lp[4] = {0.f,0.f,0.f,0.f};
    float hn[16][4];
    #pragma unroll
    for (int nt = 0; nt < 16; nt++){
      f32x4 acc = {0.f,0.f,0.f,0.f};
      const unsigned short* wrow = WhhE + (size_t)(nt*16 + l16)*HE_;
      #pragma unroll
      for (int kt = 0; kt < 8; kt++)
        acc = __builtin_amdgcn_mfma_f32_16x16x32_bf16(af[kt], *(const short8*)(wrow + kt*32 + q*8), acc, 0,0,0);
      #pragma unroll
      for (int ri = 0; ri < 4; ri++){
        int n = nt*16 + nlab[ri];
        float v = acc[ri] + bihE[n] + bhhE[n] + xr[ri]*WihE[n];
        float h = tanh_fast(v);
        hn[nt][ri] = h;
        lp[ri] += h * Wcls[n];
      }
    }
    #pragma unroll
    for (int ri = 0; ri < 4; ri++) atomicAdd(&lacc[wave][mlab[ri]], lp[ri]);
    if (lane < 16){
      float lg = lacc[wave][lane] + bc;
      Ap[(size_t)(rowbase + lane)*MSTEP_ + stp] = lg;
      xls[wave][lane] = lg;
      lacc[wave][lane] = 0.f;
    }
    #pragma unroll
    for (int nt = 0; nt < 16; nt++)
      #pragma unroll
      for (int ri = 0; ri < 4; ri++)
        H[wave][mlab[ri]][nt*16 + nlab[ri]] = f2bf(hn[nt][ri]);
  }
}

// ---------------------------------------------------------------------------
// arc_logits band gather -> float32
// ---------------------------------------------------------------------------
__global__ __launch_bounds__(256) void band_kernel(const float* __restrict__ Ap,
                                                   float* __restrict__ arc)
{
  int idx = blockIdx.x*256 + threadIdx.x;
  int c = idx % S_;
  int rr = (idx / S_) % S_;
  int b = idx / (S_*S_);
  int start = rr - MSTEP_; if (start < 0) start = 0;
  bool valid = (c >= start) && (c < rr);
  float v = 0.f;
  if (valid) v = Ap[(size_t)(b*S_ + rr)*MSTEP_ + (c - start)];
  arc[idx] = v;
}

// ---------------------------------------------------------------------------
extern "C" void kernel_launch(void* const* d_in, const int* in_sizes, int n_in,
                              void* d_out, int out_size, void* d_ws, size_t ws_size,
                              hipStream_t stream)
{
  const float* inp  = (const float*)d_in[0];
  const float* tag  = (const float*)d_in[1];
  const int*   mask = (const int*)d_in[2];
  const float* sent = (const float*)d_in[3];
  const float* Wihf = (const float*)d_in[4];
  const float* Whhf = (const float*)d_in[5];
  const float* bihf = (const float*)d_in[6];
  const float* bhhf = (const float*)d_in[7];
  const float* Wihb = (const float*)d_in[8];
  const float* Whhb = (const float*)d_in[9];
  const float* bihb = (const float*)d_in[10];
  const float* bhhb = (const float*)d_in[11];
  const float* Wg2e = (const float*)d_in[12];
  const float* bg2e = (const float*)d_in[13];
  const float* WihE = (const float*)d_in[14];
  const float* WhhE = (const float*)d_in[15];
  const float* bihE = (const float*)d_in[16];
  const float* bhhE = (const float*)d_in[17];
  const float* Wcls = (const float*)d_in[18];
  const float* bcls = (const float*)d_in[19];
  const float* bos  = (const float*)d_in[20];
  const float* Wht  = (const float*)d_in[21];
  const float* bht  = (const float*)d_in[22];
  const float* Wdt  = (const float*)d_in[23];
  const float* bdt  = (const float*)d_in[24];
  (void)in_sizes; (void)n_in; (void)out_size; (void)ws_size;

  char* ws = (char*)d_ws;
  unsigned short* preb   = (unsigned short*)ws;                       // 39,321,600 B
  unsigned short* gs     = (unsigned short*)(ws + 39321600);          // 39,321,600 B
  unsigned int*   P      = (unsigned int*)(ws + 78643200);            //    640,000 B
  unsigned short* Wihcat = (unsigned short*)(ws + 79283200);          //  1,433,600 B
  unsigned short* Wg2e_b = (unsigned short*)(ws + 80716800);          //    409,600 B
  unsigned short* Wtag_b = (unsigned short*)(ws + 81126400);          //    409,600 B
  unsigned short* WhhE_b = (unsigned short*)(ws + 81536000);          //    131,072 B  (end ~81.7 MB)
  // preb is dead after rnn_kernel; proj/Ap alias into it.
  float*          proj   = (float*)ws;                                // 25,165,824 B (alias)
  float*          Ap     = (float*)(ws + 25165824);                   //  1,966,080 B (alias)

  float* outH   = (float*)d_out;                 // f32: reference output dtype
  float* outArc = outH + 2*HEAD_SZ_;

  hipLaunchKernelGGL(cvt4, dim3(350), dim3(256), 0, stream, Wihf, Wihcat,           400*896/4);
  hipLaunchKernelGGL(cvt4, dim3(350), dim3(256), 0, stream, Wihb, Wihcat + 400*896, 400*896/4);
  hipLaunchKernelGGL(cvt4, dim3(200), dim3(256), 0, stream, Wg2e, Wg2e_b,           256*800/4);
  hipLaunchKernelGGL(cvt4, dim3(100), dim3(256), 0, stream, Wht,  Wtag_b,           128*800/4);
  hipLaunchKernelGGL(cvt4, dim3(100), dim3(256), 0, stream, Wdt,  Wtag_b + 128*800, 128*800/4);
  hipLaunchKernelGGL(cvt4, dim3(64),  dim3(256), 0, stream, WhhE, WhhE_b,           256*256/4);
  hipLaunchKernelGGL(pack_whh, dim3(313), dim3(256), 0, stream, Whhf, Whhb, P);
  hipLaunchKernelGGL(gemm_pre, dim3(9600), dim3(256), 0, stream,
                     inp, tag, sent, Wihcat, bihf, bhhf, bihb, bhhb, preb);
  hipLaunchKernelGGL(rnn_kernel, dim3(128), dim3(448), 0, stream, preb, P, mask, gs);
  hipLaunchKernelGGL(gemm_proj, dim3(3072), dim3(256), 0, stream, gs, Wg2e_b, bg2e, proj);
  hipLaunchKernelGGL(gemm_tag,  dim3(3072), dim3(256), 0, stream, gs, Wtag_b, bht, bdt, outH);
  hipLaunchKernelGGL(estep_kernel, dim3(384), dim3(256), 0, stream,
                     proj, WhhE_b, bihE, bhhE, WihE, Wcls, bcls, bos, Ap);
  hipLaunchKernelGGL(band_kernel, dim3(36864), dim3(256), 0, stream, Ap, outArc);
}

// Round 6
// 6604.417 us; speedup vs baseline: 1.0598x; 1.0598x over previous
//
#include <hip/hip_runtime.h>

#define B_ 64
#define T_ 383
#define S_ 384
#define ENC_ 768
#define TAGD_ 128
#define D_ 896
#define HG_ 400
#define HE_ 256
#define MSTEP_ 20
#define RTOT_ (B_*S_)                    // 24576
#define HEAD_SZ_ ((size_t)RTOT_*TAGD_)   // 3145728

typedef short short8 __attribute__((ext_vector_type(8)));
typedef float f32x4 __attribute__((ext_vector_type(4)));

__device__ __forceinline__ float bf2f(unsigned short u){
  union { unsigned int i; float f; } v; v.i = ((unsigned int)u) << 16; return v.f;
}
__device__ __forceinline__ float lo_f(unsigned int u){
  union { unsigned int i; float f; } v; v.i = u << 16; return v.f;
}
__device__ __forceinline__ float hi_f(unsigned int u){
  union { unsigned int i; float f; } v; v.i = u & 0xffff0000u; return v.f;
}
__device__ __forceinline__ unsigned short f2bf(float f){
  union { float f; unsigned int i; } v; v.f = f;
  unsigned int r = (v.i + 0x7fffu + ((v.i >> 16) & 1u)) >> 16;
  return (unsigned short)r;
}
__device__ __forceinline__ float tanh_fast(float x){
  float xc = fminf(fmaxf(x, -15.f), 15.f);
  float e = __expf(2.f*xc);
  return (e - 1.f) / (e + 1.f);
}

// ---------------------------------------------------------------------------
// Runtime MFMA C/D-layout discovery (probe MFMAs). Epilogues scatter via the
// discovered (row,col) maps, so no hard-coded fragment-layout assumption.
// ---------------------------------------------------------------------------
__device__ __forceinline__ void probe_maps(int lane, int* mlab, int* nlab){
  unsigned short lb = f2bf((float)(lane & 15));
  short8 av, bv;
  #pragma unroll
  for (int j = 0; j < 8; j++){ av[j] = (short)lb; bv[j] = (short)0x3F80; } // bf16(1.0)
  f32x4 z = {0.f,0.f,0.f,0.f};
  f32x4 d1 = __builtin_amdgcn_mfma_f32_16x16x32_bf16(av, bv, z, 0, 0, 0);
  f32x4 d2 = __builtin_amdgcn_mfma_f32_16x16x32_bf16(bv, av, z, 0, 0, 0);
  #pragma unroll
  for (int i = 0; i < 4; i++){
    mlab[i] = (int)(d1[i]*0.03125f + 0.5f);
    nlab[i] = (int)(d2[i]*0.03125f + 0.5f);
  }
}

// Generic float -> bf16 (n multiple of 4)
__global__ __launch_bounds__(256) void cvt4(const float* __restrict__ src,
                                            unsigned short* __restrict__ dst, int n4)
{
  int i = blockIdx.x*256 + threadIdx.x;
  if (i >= n4) return;
  float4 v = ((const float4*)src)[i];
  ((ushort4*)dst)[i] = make_ushort4(f2bf(v.x), f2bf(v.y), f2bf(v.z), f2bf(v.w));
}

// ---------------------------------------------------------------------------
// Pack Whh_f / Whh_b (float) into k-major bf16-pair layout for the RNN.
// ---------------------------------------------------------------------------
__global__ __launch_bounds__(256) void pack_whh(const float* __restrict__ Wf,
                                                const float* __restrict__ Wb,
                                                unsigned int* __restrict__ P)
{
  int idx = blockIdx.x*256 + threadIdx.x;
  if (idx >= 2*100*400) return;
  int dir = idx / 40000; int rem = idx % 40000;
  int kk = rem / 400;    int j   = rem % 400;
  const float* W = dir ? Wb : Wf;
  const float* src = W + (size_t)j*HG_ + kk*4;
  unsigned int p0 = (unsigned int)f2bf(src[0]) | ((unsigned int)f2bf(src[1]) << 16);
  unsigned int p1 = (unsigned int)f2bf(src[2]) | ((unsigned int)f2bf(src[3]) << 16);
  ((uint2*)P)[idx] = make_uint2(p0, p1);
}

// ---------------------------------------------------------------------------
// pre[r][n] (n<400: fwd, else bwd) = X[r].Wihcat[n] + bih[n] + bhh[n], bf16 out.
// X = concat(sentinel / input|tag) read from f32 inputs, cast inline.
// ---------------------------------------------------------------------------
__global__ __launch_bounds__(256) void gemm_pre(
    const float* __restrict__ inp, const float* __restrict__ tag,
    const float* __restrict__ sent, const unsigned short* __restrict__ W,
    const float* __restrict__ bihf, const float* __restrict__ bhhf,
    const float* __restrict__ bihb, const float* __restrict__ bhhb,
    unsigned short* __restrict__ preb)
{
  int wid = blockIdx.x*4 + (threadIdx.x >> 6);
  int lane = threadIdx.x & 63;
  int q = lane >> 4, l16 = lane & 15;
  int mt = wid / 25, ct = wid % 25;
  int r = mt*16 + l16;
  int s = r % S_, b = r / S_;
  int mlab[4], nlab[4];
  probe_maps(lane, mlab, nlab);
  int n0 = ct*32 + l16, n1 = n0 + 16;
  const unsigned short* w0 = W + (size_t)n0*D_;
  const unsigned short* w1 = W + (size_t)n1*D_;
  f32x4 acc0 = {0.f,0.f,0.f,0.f}, acc1 = {0.f,0.f,0.f,0.f};
  for (int k0 = 0; k0 < D_; k0 += 32){
    int k = k0 + q*8;   // 8-float group never straddles the 768 boundary
    const float* asrc = (s == 0) ? (sent + k)
        : ((k < ENC_) ? inp + (size_t)(b*T_ + (s-1))*ENC_ + k
                      : tag + (size_t)(b*T_ + (s-1))*TAGD_ + (k - ENC_));
    float4 v0 = *(const float4*)asrc;
    float4 v1 = *(const float4*)(asrc + 4);
    short8 a;
    a[0]=(short)f2bf(v0.x); a[1]=(short)f2bf(v0.y); a[2]=(short)f2bf(v0.z); a[3]=(short)f2bf(v0.w);
    a[4]=(short)f2bf(v1.x); a[5]=(short)f2bf(v1.y); a[6]=(short)f2bf(v1.z); a[7]=(short)f2bf(v1.w);
    acc0 = __builtin_amdgcn_mfma_f32_16x16x32_bf16(a, *(const short8*)(w0 + k), acc0, 0,0,0);
    acc1 = __builtin_amdgcn_mfma_f32_16x16x32_bf16(a, *(const short8*)(w1 + k), acc1, 0,0,0);
  }
  #pragma unroll
  for (int i = 0; i < 4; i++){
    int row = mt*16 + mlab[i];
    int c0 = ct*32 + nlab[i], c1 = c0 + 16;
    float bb0 = (c0 < HG_) ? (bihf[c0] + bhhf[c0]) : (bihb[c0-HG_] + bhhb[c0-HG_]);
    float bb1 = (c1 < HG_) ? (bihf[c1] + bhhf[c1]) : (bihb[c1-HG_] + bhhb[c1-HG_]);
    preb[(size_t)row*800 + c0] = f2bf(acc0[i] + bb0);
    preb[(size_t)row*800 + c1] = f2bf(acc1[i] + bb1);
  }
}

// ---------------------------------------------------------------------------
// Sequential masked RNN: one block per (direction, batch) chain.
// h fp32 in LDS; Whh bf16-packed streamed (coalesced); pre read as bf16.
// ---------------------------------------------------------------------------
__global__ __launch_bounds__(448) void rnn_kernel(
    const unsigned short* __restrict__ preb, const unsigned int* __restrict__ P,
    const int* __restrict__ mask, unsigned short* __restrict__ gs)
{
  __shared__ __align__(16) float hl[400];
  int j = threadIdx.x;
  int dir = blockIdx.x >> 6, b = blockIdx.x & 63;
  const uint2* P2 = (const uint2*)P + (size_t)dir*40000;
  float hold = 0.f;
  if (j < HG_) hl[j] = 0.f;
  __syncthreads();
  for (int stp = 0; stp < S_; stp++){
    int t = dir ? (S_-1-stp) : stp;
    float hn = 0.f;
    if (j < HG_){
      float acc = bf2f(preb[(size_t)(b*S_ + t)*800 + dir*HG_ + j]);
      #pragma unroll 4
      for (int kk = 0; kk < 100; kk++){
        float4 h4 = *(const float4*)&hl[kk*4];
        uint2 u = P2[kk*400 + j];
        acc += lo_f(u.x)*h4.x + hi_f(u.x)*h4.y + lo_f(u.y)*h4.z + hi_f(u.y)*h4.w;
      }
      hn = tanh_fast(acc);
    }
    float mval = (t > 0) ? (float)mask[b*T_ + (t-1)] : 1.f;
    float hnew = mval*hn + (1.f - mval)*hold;
    __syncthreads();            // all k-loop reads of hl done
    if (j < HG_){
      hl[j] = hnew; hold = hnew;
      gs[(size_t)(b*S_ + t)*800 + dir*HG_ + j] = f2bf(hnew*mval);
    }
    __syncthreads();
  }
}

// ---------------------------------------------------------------------------
// proj[r][n] = gs[r] . Wg2e[n] + bg2e[n]   (K=800, N=256), fp32 out
// ---------------------------------------------------------------------------
__global__ __launch_bounds__(256) void gemm_proj(
    const unsigned short* __restrict__ gs, const unsigned short* __restrict__ Wg2e,
    const float* __restrict__ bg2e, float* __restrict__ proj)
{
  int wid = blockIdx.x*4 + (threadIdx.x >> 6);
  int lane = threadIdx.x & 63;
  int q = lane >> 4, l16 = lane & 15;
  int mt = wid >> 3, ct = wid & 7;
  int mlab[4], nlab[4];
  probe_maps(lane, mlab, nlab);
  const unsigned short* arow = gs + (size_t)(mt*16 + l16)*800;
  int n0 = ct*32 + l16, n1 = n0 + 16;
  const unsigned short* w0 = Wg2e + (size_t)n0*800;
  const unsigned short* w1 = Wg2e + (size_t)n1*800;
  f32x4 acc0 = {0.f,0.f,0.f,0.f}, acc1 = {0.f,0.f,0.f,0.f};
  for (int k0 = 0; k0 < 800; k0 += 32){
    int k = k0 + q*8;
    short8 a = *(const short8*)(arow + k);
    acc0 = __builtin_amdgcn_mfma_f32_16x16x32_bf16(a, *(const short8*)(w0 + k), acc0, 0,0,0);
    acc1 = __builtin_amdgcn_mfma_f32_16x16x32_bf16(a, *(const short8*)(w1 + k), acc1, 0,0,0);
  }
  #pragma unroll
  for (int i = 0; i < 4; i++){
    int row = mt*16 + mlab[i];
    int c0 = ct*32 + nlab[i], c1 = c0 + 16;
    proj[(size_t)row*HE_ + c0] = acc0[i] + bg2e[c0];
    proj[(size_t)row*HE_ + c1] = acc1[i] + bg2e[c1];
  }
}

// ---------------------------------------------------------------------------
// head_tag / dep_tag = elu(gs @ Wtag^T + b), N=256 (c<128 head, else dep).
// float32 stores into d_out.
// ---------------------------------------------------------------------------
__global__ __launch_bounds__(256) void gemm_tag(
    const unsigned short* __restrict__ gs, const unsigned short* __restrict__ Wtag,
    const float* __restrict__ bht, const float* __restrict__ bdt,
    float* __restrict__ outH)
{
  int wid = blockIdx.x*4 + (threadIdx.x >> 6);
  int lane = threadIdx.x & 63;
  int q = lane >> 4, l16 = lane & 15;
  int mt = wid >> 3, ct = wid & 7;
  int mlab[4], nlab[4];
  probe_maps(lane, mlab, nlab);
  const unsigned short* arow = gs + (size_t)(mt*16 + l16)*800;
  int n0 = ct*32 + l16, n1 = n0 + 16;
  const unsigned short* w0 = Wtag + (size_t)n0*800;
  const unsigned short* w1 = Wtag + (size_t)n1*800;
  f32x4 acc0 = {0.f,0.f,0.f,0.f}, acc1 = {0.f,0.f,0.f,0.f};
  for (int k0 = 0; k0 < 800; k0 += 32){
    int k = k0 + q*8;
    short8 a = *(const short8*)(arow + k);
    acc0 = __builtin_amdgcn_mfma_f32_16x16x32_bf16(a, *(const short8*)(w0 + k), acc0, 0,0,0);
    acc1 = __builtin_amdgcn_mfma_f32_16x16x32_bf16(a, *(const short8*)(w1 + k), acc1, 0,0,0);
  }
  #pragma unroll
  for (int i = 0; i < 4; i++){
    int row = mt*16 + mlab[i];
    int c0 = ct*32 + nlab[i], c1 = c0 + 16;
    float v0 = acc0[i] + ((c0 < TAGD_) ? bht[c0] : bdt[c0-TAGD_]);
    float v1 = acc1[i] + ((c1 < TAGD_) ? bht[c1] : bdt[c1-TAGD_]);
    v0 = (v0 > 0.f) ? v0 : expm1f(v0);
    v1 = (v1 > 0.f) ? v1 : expm1f(v1);
    if (c0 < TAGD_) outH[(size_t)row*TAGD_ + c0] = v0;
    else            outH[HEAD_SZ_ + (size_t)row*TAGD_ + (c0-TAGD_)] = v0;
    if (c1 < TAGD_) outH[(size_t)row*TAGD_ + c1] = v1;
    else            outH[HEAD_SZ_ + (size_t)row*TAGD_ + (c1-TAGD_)] = v1;
  }
}

// ---------------------------------------------------------------------------
// estep scan: each wave owns 16 rows, fully wave-private (no __syncthreads).
// Spill-free rewrite: h written to LDS immediately per nt-tile (no hn[16][4]
// register buffer). Safe within-wave: A-frags (af[8]) are register-resident
// before the nt loop, and a wave's LDS ops execute in program order.
// 2 waves per block (128 thr) for balanced 3 blocks/CU.
// ---------------------------------------------------------------------------
#define HSTR 264  // shorts per LDS row (256 + 8 pad)
__global__ __launch_bounds__(128) void estep_kernel(
    const float* __restrict__ proj, const unsigned short* __restrict__ WhhE,
    const float* __restrict__ bihE, const float* __restrict__ bhhE,
    const float* __restrict__ WihE, const float* __restrict__ Wcls,
    const float* __restrict__ bclsp, const float* __restrict__ bosp,
    float* __restrict__ Ap)
{
  __shared__ __align__(16) unsigned short H[2][16][HSTR];
  __shared__ float xls[2][16];
  __shared__ float lacc[2][16];
  int wave = threadIdx.x >> 6, lane = threadIdx.x & 63;
  int q = lane >> 4, l16 = lane & 15;
  int rowbase = (blockIdx.x*2 + wave)*16;
  int mlab[4], nlab[4];
  probe_maps(lane, mlab, nlab);
  for (int i = lane; i < 16*HE_; i += 64){
    int m = i >> 8, n = i & 255;
    H[wave][m][n] = f2bf(proj[(size_t)(rowbase+m)*HE_ + n]);
  }
  if (lane < 16){ xls[wave][lane] = bosp[0]; lacc[wave][lane] = 0.f; }
  float bc = bclsp[0];
  for (int stp = 0; stp < MSTEP_; stp++){
    short8 af[8];
    #pragma unroll
    for (int kt = 0; kt < 8; kt++)
      af[kt] = *(const short8*)&H[wave][l16][kt*32 + q*8];
    float xr[4];
    #pragma unroll
    for (int ri = 0; ri < 4; ri++) xr[ri] = xls[wave][mlab[ri]];
    float lp[4] = {0.f,0.f,0.f,0.f};
    #pragma unroll
    for (int nt = 0; nt < 16; nt++){
      f32x4 acc = {0.f,0.f,0.f,0.f};
      const unsigned short* wrow = WhhE + (size_t)(nt*16 + l16)*HE_;
      #pragma unroll
      for (int kt = 0; kt < 8; kt++)
        acc = __builtin_amdgcn_mfma_f32_16x16x32_bf16(af[kt], *(const short8*)(wrow + kt*32 + q*8), acc, 0,0,0);
      #pragma unroll
      for (int ri = 0; ri < 4; ri++){
        int n = nt*16 + nlab[ri];
        float v = acc[ri] + bihE[n] + bhhE[n] + xr[ri]*WihE[n];
        float h = tanh_fast(v);
        lp[ri] += h * Wcls[n];
        H[wave][mlab[ri]][n] = f2bf(h);   // immediate LDS write, no register buffer
      }
    }
    #pragma unroll
    for (int ri = 0; ri < 4; ri++) atomicAdd(&lacc[wave][mlab[ri]], lp[ri]);
    if (lane < 16){
      float lg = lacc[wave][lane] + bc;
      Ap[(size_t)(rowbase + lane)*MSTEP_ + stp] = lg;
      xls[wave][lane] = lg;
      lacc[wave][lane] = 0.f;
    }
  }
}

// ---------------------------------------------------------------------------
// arc_logits band gather -> float32
// ---------------------------------------------------------------------------
__global__ __launch_bounds__(256) void band_kernel(const float* __restrict__ Ap,
                                                   float* __restrict__ arc)
{
  int idx = blockIdx.x*256 + threadIdx.x;
  int c = idx % S_;
  int rr = (idx / S_) % S_;
  int b = idx / (S_*S_);
  int start = rr - MSTEP_; if (start < 0) start = 0;
  bool valid = (c >= start) && (c < rr);
  float v = 0.f;
  if (valid) v = Ap[(size_t)(b*S_ + rr)*MSTEP_ + (c - start)];
  arc[idx] = v;
}

// ---------------------------------------------------------------------------
extern "C" void kernel_launch(void* const* d_in, const int* in_sizes, int n_in,
                              void* d_out, int out_size, void* d_ws, size_t ws_size,
                              hipStream_t stream)
{
  const float* inp  = (const float*)d_in[0];
  const float* tag  = (const float*)d_in[1];
  const int*   mask = (const int*)d_in[2];
  const float* sent = (const float*)d_in[3];
  const float* Wihf = (const float*)d_in[4];
  const float* Whhf = (const float*)d_in[5];
  const float* bihf = (const float*)d_in[6];
  const float* bhhf = (const float*)d_in[7];
  const float* Wihb = (const float*)d_in[8];
  const float* Whhb = (const float*)d_in[9];
  const float* bihb = (const float*)d_in[10];
  const float* bhhb = (const float*)d_in[11];
  const float* Wg2e = (const float*)d_in[12];
  const float* bg2e = (const float*)d_in[13];
  const float* WihE = (const float*)d_in[14];
  const float* WhhE = (const float*)d_in[15];
  const float* bihE = (const float*)d_in[16];
  const float* bhhE = (const float*)d_in[17];
  const float* Wcls = (const float*)d_in[18];
  const float* bcls = (const float*)d_in[19];
  const float* bos  = (const float*)d_in[20];
  const float* Wht  = (const float*)d_in[21];
  const float* bht  = (const float*)d_in[22];
  const float* Wdt  = (const float*)d_in[23];
  const float* bdt  = (const float*)d_in[24];
  (void)in_sizes; (void)n_in; (void)out_size; (void)ws_size;

  char* ws = (char*)d_ws;
  unsigned short* preb   = (unsigned short*)ws;                       // 39,321,600 B
  unsigned short* gs     = (unsigned short*)(ws + 39321600);          // 39,321,600 B
  unsigned int*   P      = (unsigned int*)(ws + 78643200);            //    640,000 B
  unsigned short* Wihcat = (unsigned short*)(ws + 79283200);          //  1,433,600 B
  unsigned short* Wg2e_b = (unsigned short*)(ws + 80716800);          //    409,600 B
  unsigned short* Wtag_b = (unsigned short*)(ws + 81126400);          //    409,600 B
  unsigned short* WhhE_b = (unsigned short*)(ws + 81536000);          //    131,072 B  (end ~81.7 MB)
  // preb is dead after rnn_kernel; proj/Ap alias into it.
  float*          proj   = (float*)ws;                                // 25,165,824 B (alias)
  float*          Ap     = (float*)(ws + 25165824);                   //  1,966,080 B (alias)

  float* outH   = (float*)d_out;                 // f32: reference output dtype
  float* outArc = outH + 2*HEAD_SZ_;

  hipLaunchKernelGGL(cvt4, dim3(350), dim3(256), 0, stream, Wihf, Wihcat,           400*896/4);
  hipLaunchKernelGGL(cvt4, dim3(350), dim3(256), 0, stream, Wihb, Wihcat + 400*896, 400*896/4);
  hipLaunchKernelGGL(cvt4, dim3(200), dim3(256), 0, stream, Wg2e, Wg2e_b,           256*800/4);
  hipLaunchKernelGGL(cvt4, dim3(100), dim3(256), 0, stream, Wht,  Wtag_b,           128*800/4);
  hipLaunchKernelGGL(cvt4, dim3(100), dim3(256), 0, stream, Wdt,  Wtag_b + 128*800, 128*800/4);
  hipLaunchKernelGGL(cvt4, dim3(64),  dim3(256), 0, stream, WhhE, WhhE_b,           256*256/4);
  hipLaunchKernelGGL(pack_whh, dim3(313), dim3(256), 0, stream, Whhf, Whhb, P);
  hipLaunchKernelGGL(gemm_pre, dim3(9600), dim3(256), 0, stream,
                     inp, tag, sent, Wihcat, bihf, bhhf, bihb, bhhb, preb);
  hipLaunchKernelGGL(rnn_kernel, dim3(128), dim3(448), 0, stream, preb, P, mask, gs);
  hipLaunchKernelGGL(gemm_proj, dim3(3072), dim3(256), 0, stream, gs, Wg2e_b, bg2e, proj);
  hipLaunchKernelGGL(gemm_tag,  dim3(3072), dim3(256), 0, stream, gs, Wtag_b, bht, bdt, outH);
  hipLaunchKernelGGL(estep_kernel, dim3(768), dim3(128), 0, stream,
                     proj, WhhE_b, bihE, bhhE, WihE, Wcls, bcls, bos, Ap);
  hipLaunchKernelGGL(band_kernel, dim3(36864), dim3(256), 0, stream, Ap, outArc);
}